// Round 18
// baseline (237.161 us; speedup 1.0000x reference)
//
#include <hip/hip_runtime.h>

#define DIM 256
// contiguous combined layout (query path): per node 3 slots (x, oh, th)
#define NODE_U2 192
#define NODE_U4 96
#define SLOT_OH_U4 32
#define SLOT_TH_U4 64

// dimension slicing (gather path): 8 slices x 32 dims (64 B = 4 uint4)
#define NSL 8
// LDS edge-stage capacity (u16)
#define ECAP 2048

typedef unsigned int u32x2 __attribute__((ext_vector_type(2)));
typedef unsigned int u32x4 __attribute__((ext_vector_type(4)));

// ---- bf16 helpers ---------------------------------------------------------
__device__ __forceinline__ unsigned int f2bf_rne(float f) {
    unsigned int u = __float_as_uint(f);
    return (u + 0x7fffu + ((u >> 16) & 1u)) >> 16;
}
__device__ __forceinline__ float bf_lo(unsigned int u) {
    return __uint_as_float(u << 16);
}
__device__ __forceinline__ float bf_hi(unsigned int u) {
    return __uint_as_float(u & 0xffff0000u);
}
__device__ __forceinline__ unsigned int pack2(float a, float b) {
    return f2bf_rne(a) | (f2bf_rne(b) << 16);
}

#define ACC8(v)                                            \
    do {                                                   \
        a0 += bf_lo((v).x); a1 += bf_hi((v).x);            \
        a2 += bf_lo((v).y); a3 += bf_hi((v).y);            \
        a4 += bf_lo((v).z); a5 += bf_hi((v).z);            \
        a6 += bf_lo((v).w); a7 += bf_hi((v).w);            \
    } while (0)

// ---------------------------------------------------------------------------
// 1) fused x + hist. Stream section in TWO destination-linear passes:
//    pass A: cmb x-slot (linear over nv; coalesced read+write)
//    pass B: xs_sl (linear over xs_sl; nv re-read is L3-warm; coalesced write)
//    then the XCD-partitioned degree histogram.
// ---------------------------------------------------------------------------
__global__ void x_and_hist_kernel(const float* __restrict__ nv,
                                  const float* __restrict__ w,
                                  uint2* __restrict__ cmb,
                                  uint2* __restrict__ xs_sl,
                                  int total_u2, int N,
                                  const int* __restrict__ adj_row,
                                  int* __restrict__ cnt, int E, int per_part) {
    int i0 = blockIdx.x * blockDim.x + threadIdx.x;
    int stride = gridDim.x * blockDim.x;
    const float4* nv4 = reinterpret_cast<const float4*>(nv);

    // pass A: contiguous cmb x-slot
    for (int i = i0; i < total_u2; i += stride) {
        float4 v = nv4[i];
        int node = i >> 6;
        int j = i & 63;
        float wt = w[node];
        u32x2 r;
        r.x = pack2(v.x * wt, v.y * wt);
        r.y = pack2(v.z * wt, v.w * wt);
        __builtin_nontemporal_store(
            r, reinterpret_cast<u32x2*>(&cmb[(size_t)node * NODE_U2 + j]));
    }

    // pass B: sliced slab, destination-linear (fully coalesced writes)
    int perslice = N * 8;                  // uint2 per slice
    for (int i = i0; i < total_u2; i += stride) {
        int s = i / perslice;
        int rem = i - s * perslice;
        int node = rem >> 3;
        int jj = rem & 7;
        float4 v = nv4[(size_t)node * 64 + s * 8 + jj];   // L3-warm re-read
        float wt = w[node];
        u32x2 r;
        r.x = pack2(v.x * wt, v.y * wt);
        r.y = pack2(v.z * wt, v.w * wt);
        __builtin_nontemporal_store(r, reinterpret_cast<u32x2*>(&xs_sl[i]));
    }

    // histogram (XCD-partitioned)
    int bp = blockIdx.x & 7;
    unsigned lo = (unsigned)(bp * per_part);
    int chunk = blockIdx.x >> 3;
    int nchunks = gridDim.x >> 3;
    int E4 = E >> 2;
    for (int i = chunk * 256 + threadIdx.x; i < E4; i += nchunks * 256) {
        int4 r4 = reinterpret_cast<const int4*>(adj_row)[i];
        if ((unsigned)(r4.x - lo) < (unsigned)per_part) atomicAdd(&cnt[r4.x], 1);
        if ((unsigned)(r4.y - lo) < (unsigned)per_part) atomicAdd(&cnt[r4.y], 1);
        if ((unsigned)(r4.z - lo) < (unsigned)per_part) atomicAdd(&cnt[r4.z], 1);
        if ((unsigned)(r4.w - lo) < (unsigned)per_part) atomicAdd(&cnt[r4.w], 1);
    }
    if (bp == 0 && chunk == 0) {
        for (int e = (E & ~3) + threadIdx.x; e < E; e += 256)
            atomicAdd(&cnt[adj_row[e]], 1);
    }
}

// ---------------------------------------------------------------------------
// generic 2-level scan pieces
// ---------------------------------------------------------------------------
__global__ void block_sum_kernel(const int* __restrict__ in,
                                 int* __restrict__ sums, int n) {
    __shared__ int lds[256];
    int i = blockIdx.x * 256 + threadIdx.x;
    lds[threadIdx.x] = (i < n) ? in[i] : 0;
    __syncthreads();
    #pragma unroll
    for (int off = 128; off > 0; off >>= 1) {
        if (threadIdx.x < off) lds[threadIdx.x] += lds[threadIdx.x + off];
        __syncthreads();
    }
    if (threadIdx.x == 0) sums[blockIdx.x] = lds[0];
}

__global__ void scan_sums_kernel(int* __restrict__ sums, int nb,
                                 int* __restrict__ total_out) {
    __shared__ int lds[256];
    int v = (threadIdx.x < nb) ? sums[threadIdx.x] : 0;
    lds[threadIdx.x] = v;
    __syncthreads();
    #pragma unroll
    for (int off = 1; off < 256; off <<= 1) {
        int t = (threadIdx.x >= off) ? lds[threadIdx.x - off] : 0;
        __syncthreads();
        lds[threadIdx.x] += t;
        __syncthreads();
    }
    if (threadIdx.x < nb) sums[threadIdx.x] = lds[threadIdx.x] - v;
    if (threadIdx.x == 255) *total_out = lds[255];
}

__global__ void scan_block_kernel(const int* __restrict__ in,
                                  const int* __restrict__ sums,
                                  int* __restrict__ out1,
                                  int* __restrict__ out2, int n) {
    __shared__ int lds[256];
    int i = blockIdx.x * 256 + threadIdx.x;
    int v = (i < n) ? in[i] : 0;
    lds[threadIdx.x] = v;
    __syncthreads();
    #pragma unroll
    for (int off = 1; off < 256; off <<= 1) {
        int t = (threadIdx.x >= off) ? lds[threadIdx.x - off] : 0;
        __syncthreads();
        lds[threadIdx.x] += t;
        __syncthreads();
    }
    if (i < n) {
        int excl = sums[blockIdx.x] + lds[threadIdx.x] - v;
        out1[i] = excl;
        out2[i] = excl;
    }
}

// ---------------------------------------------------------------------------
// XCD-partitioned permutation build; perm stored as u16 (N < 65536)
// ---------------------------------------------------------------------------
__global__ void scatter_perm_part_kernel(const int* __restrict__ row,
                                         const int* __restrict__ col,
                                         int* __restrict__ cursor,
                                         unsigned short* __restrict__ perm,
                                         int E, int per_part) {
    int bp = blockIdx.x & 7;
    unsigned lo = (unsigned)(bp * per_part);
    int chunk = blockIdx.x >> 3;
    int nchunks = gridDim.x >> 3;
    int E4 = E >> 2;
    for (int i = chunk * 256 + threadIdx.x; i < E4; i += nchunks * 256) {
        int4 r4 = reinterpret_cast<const int4*>(row)[i];
        int e = i << 2;
        if ((unsigned)(r4.x - lo) < (unsigned)per_part) {
            int pos = atomicAdd(&cursor[r4.x], 1);
            perm[pos] = (unsigned short)col[e];
        }
        if ((unsigned)(r4.y - lo) < (unsigned)per_part) {
            int pos = atomicAdd(&cursor[r4.y], 1);
            perm[pos] = (unsigned short)col[e + 1];
        }
        if ((unsigned)(r4.z - lo) < (unsigned)per_part) {
            int pos = atomicAdd(&cursor[r4.z], 1);
            perm[pos] = (unsigned short)col[e + 2];
        }
        if ((unsigned)(r4.w - lo) < (unsigned)per_part) {
            int pos = atomicAdd(&cursor[r4.w], 1);
            perm[pos] = (unsigned short)col[e + 3];
        }
    }
    if (bp == 0 && chunk == 0) {
        for (int e = (E & ~3) + threadIdx.x; e < E; e += 256) {
            int pos = atomicAdd(&cursor[row[e]], 1);
            perm[pos] = (unsigned short)col[e];
        }
    }
}

// ---------------------------------------------------------------------------
// Dimension-sliced gather with LDS-staged u16 edge lists; NT dst stores keep
// the per-XCD 3.2MB src slab L2-resident.
// ---------------------------------------------------------------------------
__global__ void gather_sliced_kernel(const int* __restrict__ row_ptr,
                                     const unsigned short* __restrict__ perm,
                                     const uint4* __restrict__ src_sl,
                                     uint4* __restrict__ dst_sl,
                                     uint4* __restrict__ dst_cmb_slot,
                                     int N) {
    __shared__ unsigned short eidx[ECAP];
    int s = blockIdx.x & (NSL - 1);
    int rb = blockIdx.x >> 3;
    int r0 = rb * 64;
    int rlim = r0 + 64 < N ? r0 + 64 : N;
    int beg0 = row_ptr[r0];
    int end0 = row_ptr[rlim];
    int L = end0 - beg0;
    int Lc = L < ECAP ? L : ECAP;
    for (int i = threadIdx.x; i < Lc; i += 256) eidx[i] = perm[beg0 + i];
    __syncthreads();

    int g = threadIdx.x >> 2;
    int j = threadIdx.x & 3;
    int r = r0 + g;
    if (r >= N) return;

    int beg = row_ptr[r];
    int end = row_ptr[r + 1];
    const uint4* base = src_sl + (size_t)s * N * 4;

    float a0 = 0.f, a1 = 0.f, a2 = 0.f, a3 = 0.f;
    float a4 = 0.f, a5 = 0.f, a6 = 0.f, a7 = 0.f;

    if (L <= ECAP) {
        int o = beg - beg0;
        int cnt = end - beg;
        int k = 0;
        for (; k + 3 < cnt; k += 4) {
            int c0 = eidx[o + k];
            int c1 = eidx[o + k + 1];
            int c2 = eidx[o + k + 2];
            int c3 = eidx[o + k + 3];
            uint4 v0 = base[(size_t)c0 * 4 + j];
            uint4 v1 = base[(size_t)c1 * 4 + j];
            uint4 v2 = base[(size_t)c2 * 4 + j];
            uint4 v3 = base[(size_t)c3 * 4 + j];
            ACC8(v0); ACC8(v1); ACC8(v2); ACC8(v3);
        }
        for (; k < cnt; ++k) {
            uint4 v = base[(size_t)eidx[o + k] * 4 + j];
            ACC8(v);
        }
    } else {
        for (int e = beg; e < end; ++e) {
            uint4 v = base[(size_t)perm[e] * 4 + j];
            ACC8(v);
        }
    }

    u32x4 o4;
    o4.x = pack2(a0, a1);
    o4.y = pack2(a2, a3);
    o4.z = pack2(a4, a5);
    o4.w = pack2(a6, a7);
    if (dst_sl)
        __builtin_nontemporal_store(
            o4, reinterpret_cast<u32x4*>(&dst_sl[((size_t)s * N + r) * 4 + j]));
    __builtin_nontemporal_store(
        o4, reinterpret_cast<u32x4*>(
                &dst_cmb_slot[(size_t)r * NODE_U4 + s * 4 + j]));
}

// ---------------------------------------------------------------------------
// Query: 32 lanes per query (uint4 loads), 2 queries per wave (contiguous cmb)
// ---------------------------------------------------------------------------
__global__ void query_kernel(const int* __restrict__ es,
                             const int* __restrict__ et,
                             const uint4* __restrict__ cmb4,
                             const int* __restrict__ deg,
                             float* __restrict__ out, int nq) {
    int gid = blockIdx.x * blockDim.x + threadIdx.x;
    int q = gid >> 5;
    if (q >= nq) return;
    int l = gid & 31;

    int s = es[q];
    int t = et[q];

    const uint4* ns = cmb4 + (size_t)s * NODE_U4;
    const uint4* nt = cmb4 + (size_t)t * NODE_U4;

    uint4 vxs = ns[l];
    uint4 vos = ns[SLOT_OH_U4 + l];
    uint4 vts = ns[SLOT_TH_U4 + l];
    uint4 vxt = nt[l];
    uint4 vot = nt[SLOT_OH_U4 + l];
    uint4 vtt = nt[SLOT_TH_U4 + l];
    float ds = (float)deg[s];
    float dt = (float)deg[t];

    float c11 = 0.f, c12 = 0.f, c22 = 0.f, cs = 0.f;
    const unsigned int* pxs = (const unsigned int*)&vxs;
    const unsigned int* pxt = (const unsigned int*)&vxt;
    const unsigned int* pos_ = (const unsigned int*)&vos;
    const unsigned int* pot = (const unsigned int*)&vot;
    const unsigned int* pts = (const unsigned int*)&vts;
    const unsigned int* ptt = (const unsigned int*)&vtt;
    #pragma unroll
    for (int k = 0; k < 4; ++k) {
        {
            float fxs = bf_lo(pxs[k]), fxt = bf_lo(pxt[k]);
            float fos = bf_lo(pos_[k]), fot = bf_lo(pot[k]);
            float fts = bf_lo(pts[k]), ftt = bf_lo(ptt[k]);
            c11 += fos * fot;
            c12 += fos * ftt + fts * fot;
            float as = fts - ds * fxs;
            float bt = ftt - dt * fxt;
            c22 += as * bt;
            cs  += fos * fts + fot * ftt;
        }
        {
            float fxs = bf_hi(pxs[k]), fxt = bf_hi(pxt[k]);
            float fos = bf_hi(pos_[k]), fot = bf_hi(pot[k]);
            float fts = bf_hi(pts[k]), ftt = bf_hi(ptt[k]);
            c11 += fos * fot;
            c12 += fos * ftt + fts * fot;
            float as = fts - ds * fxs;
            float bt = ftt - dt * fxt;
            c22 += as * bt;
            cs  += fos * fts + fot * ftt;
        }
    }

    #pragma unroll
    for (int off = 16; off > 0; off >>= 1) {
        c11 += __shfl_xor(c11, off);
        c12 += __shfl_xor(c12, off);
        c22 += __shfl_xor(c22, off);
        cs  += __shfl_xor(cs,  off);
    }

    if (l == 0) {
        out[q]          = c11;
        out[nq + q]     = c12;
        out[2 * nq + q] = c22;
        out[3 * nq + q] = cs;
    }
}

// ---------------------------------------------------------------------------
extern "C" void kernel_launch(void* const* d_in, const int* in_sizes, int n_in,
                              void* d_out, int out_size, void* d_ws, size_t ws_size,
                              hipStream_t stream) {
    const int*   edges        = (const int*)  d_in[0];
    const int*   adj_row      = (const int*)  d_in[1];
    const int*   adj_col      = (const int*)  d_in[2];
    const float* node_weight  = (const float*)d_in[3];
    const float* node_vectors = (const float*)d_in[4];

    const int EQ = in_sizes[0] / 2;
    const int E  = in_sizes[1];
    const int N  = in_sizes[3];

    // workspace layout
    uint2* cmb   = (uint2*)d_ws;                        // N*192 uint2
    uint2* xs_sl = cmb + (size_t)N * NODE_U2;           // N*64 uint2
    uint2* oh_sl = xs_sl + (size_t)N * 64;              // N*64 uint2
    int* row_ptr = (int*)(oh_sl + (size_t)N * 64);      // [N+1]
    int* cursor  = row_ptr + (N + 1);                   // [N]
    int* cnt     = cursor + N;                          // [N] (deg)
    int* s1      = cnt + N;                             // [256]
    unsigned short* perm = (unsigned short*)(s1 + 256); // [E]

    const int* es = edges;
    const int* et = edges + EQ;
    float* out = (float*)d_out;

    const int nb0 = (N + 255) / 256;   // 196
    const int per_part = (N + 7) / 8;  // 6250

    // --- fused x (two destination-linear passes) + partitioned histogram ---
    hipMemsetAsync(cnt, 0, (size_t)N * sizeof(int), stream);
    int total_u2 = N * 64;
    x_and_hist_kernel<<<2048, 256, 0, stream>>>(node_vectors, node_weight,
                                                cmb, xs_sl, total_u2, N,
                                                adj_row, cnt, E, per_part);

    // --- CSR scan + partitioned permutation (u16) ---
    block_sum_kernel<<<nb0, 256, 0, stream>>>(cnt, s1, N);
    scan_sums_kernel<<<1, 256, 0, stream>>>(s1, nb0, row_ptr + N);
    scan_block_kernel<<<nb0, 256, 0, stream>>>(cnt, s1, row_ptr, cursor, N);
    scatter_perm_part_kernel<<<2048, 256, 0, stream>>>(adj_row, adj_col,
                                                       cursor, perm, E,
                                                       per_part);

    // --- one_hop / two_hop via XCD-pinned sliced gather (NT dst) ---
    const uint4* xs4 = (const uint4*)xs_sl;
    uint4* oh4 = (uint4*)oh_sl;
    uint4* cmb4 = (uint4*)cmb;
    int nrb = (N + 63) / 64;
    int gblocks = nrb * NSL;
    gather_sliced_kernel<<<gblocks, 256, 0, stream>>>(
        row_ptr, perm, xs4, oh4, cmb4 + SLOT_OH_U4, N);
    gather_sliced_kernel<<<gblocks, 256, 0, stream>>>(
        row_ptr, perm, (const uint4*)oh4, (uint4*)nullptr,
        cmb4 + SLOT_TH_U4, N);

    // --- queries (unsorted, contiguous cmb) ---
    int qthreads = EQ * 32;
    query_kernel<<<(qthreads + 255) / 256, 256, 0, stream>>>(
        es, et, cmb4, cnt, out, EQ);
}

// Round 19
// 232.226 us; speedup vs baseline: 1.0212x; 1.0212x over previous
//
#include <hip/hip_runtime.h>

#define DIM 256
// contiguous combined layout (query path): per node 3 slots (x, oh, th)
#define NODE_U2 192
#define NODE_U4 96
#define SLOT_OH_U4 32
#define SLOT_TH_U4 64

// dimension slicing (gather path): 8 slices x 32 dims (64 B = 4 uint4)
#define NSL 8
// LDS edge-stage capacity (u16)
#define ECAP 2048

typedef unsigned int u32x2 __attribute__((ext_vector_type(2)));
typedef unsigned int u32x4 __attribute__((ext_vector_type(4)));
typedef int i32x4 __attribute__((ext_vector_type(4)));

// ---- bf16 helpers ---------------------------------------------------------
__device__ __forceinline__ unsigned int f2bf_rne(float f) {
    unsigned int u = __float_as_uint(f);
    return (u + 0x7fffu + ((u >> 16) & 1u)) >> 16;
}
__device__ __forceinline__ float bf_lo(unsigned int u) {
    return __uint_as_float(u << 16);
}
__device__ __forceinline__ float bf_hi(unsigned int u) {
    return __uint_as_float(u & 0xffff0000u);
}
__device__ __forceinline__ unsigned int pack2(float a, float b) {
    return f2bf_rne(a) | (f2bf_rne(b) << 16);
}

#define ACC8(v)                                            \
    do {                                                   \
        a0 += bf_lo((v).x); a1 += bf_hi((v).x);            \
        a2 += bf_lo((v).y); a3 += bf_hi((v).y);            \
        a4 += bf_lo((v).z); a5 += bf_hi((v).z);            \
        a6 += bf_lo((v).w); a7 += bf_hi((v).w);            \
    } while (0)

// ---------------------------------------------------------------------------
// 1) fused: x (contiguous cmb slot + sliced slab, NT stores) +
//    XCD-partitioned degree histogram (NT adj_row stream)
// ---------------------------------------------------------------------------
__global__ void x_and_hist_kernel(const float* __restrict__ nv,
                                  const float* __restrict__ w,
                                  uint2* __restrict__ cmb,
                                  uint2* __restrict__ xs_sl,
                                  int total_u2, int N,
                                  const int* __restrict__ adj_row,
                                  int* __restrict__ cnt, int E, int per_part) {
    int i0 = blockIdx.x * blockDim.x + threadIdx.x;
    int stride = gridDim.x * blockDim.x;
    for (int i = i0; i < total_u2; i += stride) {
        float4 v = reinterpret_cast<const float4*>(nv)[i];
        int node = i >> 6;
        int j = i & 63;
        float wt = w[node];
        u32x2 r;
        r.x = pack2(v.x * wt, v.y * wt);
        r.y = pack2(v.z * wt, v.w * wt);
        __builtin_nontemporal_store(
            r, reinterpret_cast<u32x2*>(&cmb[(size_t)node * NODE_U2 + j]));
        int s = j >> 3;
        __builtin_nontemporal_store(
            r, reinterpret_cast<u32x2*>(
                   &xs_sl[((size_t)s * N + node) * 8 + (j & 7)]));
    }
    int bp = blockIdx.x & 7;
    unsigned lo = (unsigned)(bp * per_part);
    int chunk = blockIdx.x >> 3;
    int nchunks = gridDim.x >> 3;
    int E4 = E >> 2;
    const i32x4* row4 = reinterpret_cast<const i32x4*>(adj_row);
    for (int i = chunk * 256 + threadIdx.x; i < E4; i += nchunks * 256) {
        i32x4 r4 = __builtin_nontemporal_load(&row4[i]);
        if ((unsigned)(r4.x - lo) < (unsigned)per_part) atomicAdd(&cnt[r4.x], 1);
        if ((unsigned)(r4.y - lo) < (unsigned)per_part) atomicAdd(&cnt[r4.y], 1);
        if ((unsigned)(r4.z - lo) < (unsigned)per_part) atomicAdd(&cnt[r4.z], 1);
        if ((unsigned)(r4.w - lo) < (unsigned)per_part) atomicAdd(&cnt[r4.w], 1);
    }
    if (bp == 0 && chunk == 0) {
        for (int e = (E & ~3) + threadIdx.x; e < E; e += 256)
            atomicAdd(&cnt[adj_row[e]], 1);
    }
}

// ---------------------------------------------------------------------------
// generic 2-level scan pieces
// ---------------------------------------------------------------------------
__global__ void block_sum_kernel(const int* __restrict__ in,
                                 int* __restrict__ sums, int n) {
    __shared__ int lds[256];
    int i = blockIdx.x * 256 + threadIdx.x;
    lds[threadIdx.x] = (i < n) ? in[i] : 0;
    __syncthreads();
    #pragma unroll
    for (int off = 128; off > 0; off >>= 1) {
        if (threadIdx.x < off) lds[threadIdx.x] += lds[threadIdx.x + off];
        __syncthreads();
    }
    if (threadIdx.x == 0) sums[blockIdx.x] = lds[0];
}

__global__ void scan_sums_kernel(int* __restrict__ sums, int nb,
                                 int* __restrict__ total_out) {
    __shared__ int lds[256];
    int v = (threadIdx.x < nb) ? sums[threadIdx.x] : 0;
    lds[threadIdx.x] = v;
    __syncthreads();
    #pragma unroll
    for (int off = 1; off < 256; off <<= 1) {
        int t = (threadIdx.x >= off) ? lds[threadIdx.x - off] : 0;
        __syncthreads();
        lds[threadIdx.x] += t;
        __syncthreads();
    }
    if (threadIdx.x < nb) sums[threadIdx.x] = lds[threadIdx.x] - v;
    if (threadIdx.x == 255) *total_out = lds[255];
}

__global__ void scan_block_kernel(const int* __restrict__ in,
                                  const int* __restrict__ sums,
                                  int* __restrict__ out1,
                                  int* __restrict__ out2, int n) {
    __shared__ int lds[256];
    int i = blockIdx.x * 256 + threadIdx.x;
    int v = (i < n) ? in[i] : 0;
    lds[threadIdx.x] = v;
    __syncthreads();
    #pragma unroll
    for (int off = 1; off < 256; off <<= 1) {
        int t = (threadIdx.x >= off) ? lds[threadIdx.x - off] : 0;
        __syncthreads();
        lds[threadIdx.x] += t;
        __syncthreads();
    }
    if (i < n) {
        int excl = sums[blockIdx.x] + lds[threadIdx.x] - v;
        out1[i] = excl;
        out2[i] = excl;
    }
}

// ---------------------------------------------------------------------------
// XCD-partitioned permutation build; perm u16; NT loads on row/col streams
// ---------------------------------------------------------------------------
__global__ void scatter_perm_part_kernel(const int* __restrict__ row,
                                         const int* __restrict__ col,
                                         int* __restrict__ cursor,
                                         unsigned short* __restrict__ perm,
                                         int E, int per_part) {
    int bp = blockIdx.x & 7;
    unsigned lo = (unsigned)(bp * per_part);
    int chunk = blockIdx.x >> 3;
    int nchunks = gridDim.x >> 3;
    int E4 = E >> 2;
    const i32x4* row4 = reinterpret_cast<const i32x4*>(row);
    const i32x4* col4 = reinterpret_cast<const i32x4*>(col);
    for (int i = chunk * 256 + threadIdx.x; i < E4; i += nchunks * 256) {
        i32x4 r4 = __builtin_nontemporal_load(&row4[i]);
        i32x4 c4 = __builtin_nontemporal_load(&col4[i]);
        if ((unsigned)(r4.x - lo) < (unsigned)per_part) {
            int pos = atomicAdd(&cursor[r4.x], 1);
            perm[pos] = (unsigned short)c4.x;
        }
        if ((unsigned)(r4.y - lo) < (unsigned)per_part) {
            int pos = atomicAdd(&cursor[r4.y], 1);
            perm[pos] = (unsigned short)c4.y;
        }
        if ((unsigned)(r4.z - lo) < (unsigned)per_part) {
            int pos = atomicAdd(&cursor[r4.z], 1);
            perm[pos] = (unsigned short)c4.z;
        }
        if ((unsigned)(r4.w - lo) < (unsigned)per_part) {
            int pos = atomicAdd(&cursor[r4.w], 1);
            perm[pos] = (unsigned short)c4.w;
        }
    }
    if (bp == 0 && chunk == 0) {
        for (int e = (E & ~3) + threadIdx.x; e < E; e += 256) {
            int pos = atomicAdd(&cursor[row[e]], 1);
            perm[pos] = (unsigned short)col[e];
        }
    }
}

// ---------------------------------------------------------------------------
// Dimension-sliced gather with LDS-staged u16 edge lists; NT dst stores keep
// the per-XCD 3.2MB src slab L2-resident.
// ---------------------------------------------------------------------------
__global__ void gather_sliced_kernel(const int* __restrict__ row_ptr,
                                     const unsigned short* __restrict__ perm,
                                     const uint4* __restrict__ src_sl,
                                     uint4* __restrict__ dst_sl,
                                     uint4* __restrict__ dst_cmb_slot,
                                     int N) {
    __shared__ unsigned short eidx[ECAP];
    int s = blockIdx.x & (NSL - 1);
    int rb = blockIdx.x >> 3;
    int r0 = rb * 64;
    int rlim = r0 + 64 < N ? r0 + 64 : N;
    int beg0 = row_ptr[r0];
    int end0 = row_ptr[rlim];
    int L = end0 - beg0;
    int Lc = L < ECAP ? L : ECAP;
    for (int i = threadIdx.x; i < Lc; i += 256) eidx[i] = perm[beg0 + i];
    __syncthreads();

    int g = threadIdx.x >> 2;
    int j = threadIdx.x & 3;
    int r = r0 + g;
    if (r >= N) return;

    int beg = row_ptr[r];
    int end = row_ptr[r + 1];
    const uint4* base = src_sl + (size_t)s * N * 4;

    float a0 = 0.f, a1 = 0.f, a2 = 0.f, a3 = 0.f;
    float a4 = 0.f, a5 = 0.f, a6 = 0.f, a7 = 0.f;

    if (L <= ECAP) {
        int o = beg - beg0;
        int cnt = end - beg;
        int k = 0;
        for (; k + 3 < cnt; k += 4) {
            int c0 = eidx[o + k];
            int c1 = eidx[o + k + 1];
            int c2 = eidx[o + k + 2];
            int c3 = eidx[o + k + 3];
            uint4 v0 = base[(size_t)c0 * 4 + j];
            uint4 v1 = base[(size_t)c1 * 4 + j];
            uint4 v2 = base[(size_t)c2 * 4 + j];
            uint4 v3 = base[(size_t)c3 * 4 + j];
            ACC8(v0); ACC8(v1); ACC8(v2); ACC8(v3);
        }
        for (; k < cnt; ++k) {
            uint4 v = base[(size_t)eidx[o + k] * 4 + j];
            ACC8(v);
        }
    } else {
        for (int e = beg; e < end; ++e) {
            uint4 v = base[(size_t)perm[e] * 4 + j];
            ACC8(v);
        }
    }

    u32x4 o4;
    o4.x = pack2(a0, a1);
    o4.y = pack2(a2, a3);
    o4.z = pack2(a4, a5);
    o4.w = pack2(a6, a7);
    if (dst_sl)
        __builtin_nontemporal_store(
            o4, reinterpret_cast<u32x4*>(&dst_sl[((size_t)s * N + r) * 4 + j]));
    __builtin_nontemporal_store(
        o4, reinterpret_cast<u32x4*>(
                &dst_cmb_slot[(size_t)r * NODE_U4 + s * 4 + j]));
}

// ---------------------------------------------------------------------------
// Query: 32 lanes per query (uint4 loads), 2 queries per wave (contiguous cmb)
// ---------------------------------------------------------------------------
__global__ void query_kernel(const int* __restrict__ es,
                             const int* __restrict__ et,
                             const uint4* __restrict__ cmb4,
                             const int* __restrict__ deg,
                             float* __restrict__ out, int nq) {
    int gid = blockIdx.x * blockDim.x + threadIdx.x;
    int q = gid >> 5;
    if (q >= nq) return;
    int l = gid & 31;

    int s = es[q];
    int t = et[q];

    const uint4* ns = cmb4 + (size_t)s * NODE_U4;
    const uint4* nt = cmb4 + (size_t)t * NODE_U4;

    uint4 vxs = ns[l];
    uint4 vos = ns[SLOT_OH_U4 + l];
    uint4 vts = ns[SLOT_TH_U4 + l];
    uint4 vxt = nt[l];
    uint4 vot = nt[SLOT_OH_U4 + l];
    uint4 vtt = nt[SLOT_TH_U4 + l];
    float ds = (float)deg[s];
    float dt = (float)deg[t];

    float c11 = 0.f, c12 = 0.f, c22 = 0.f, cs = 0.f;
    const unsigned int* pxs = (const unsigned int*)&vxs;
    const unsigned int* pxt = (const unsigned int*)&vxt;
    const unsigned int* pos_ = (const unsigned int*)&vos;
    const unsigned int* pot = (const unsigned int*)&vot;
    const unsigned int* pts = (const unsigned int*)&vts;
    const unsigned int* ptt = (const unsigned int*)&vtt;
    #pragma unroll
    for (int k = 0; k < 4; ++k) {
        {
            float fxs = bf_lo(pxs[k]), fxt = bf_lo(pxt[k]);
            float fos = bf_lo(pos_[k]), fot = bf_lo(pot[k]);
            float fts = bf_lo(pts[k]), ftt = bf_lo(ptt[k]);
            c11 += fos * fot;
            c12 += fos * ftt + fts * fot;
            float as = fts - ds * fxs;
            float bt = ftt - dt * fxt;
            c22 += as * bt;
            cs  += fos * fts + fot * ftt;
        }
        {
            float fxs = bf_hi(pxs[k]), fxt = bf_hi(pxt[k]);
            float fos = bf_hi(pos_[k]), fot = bf_hi(pot[k]);
            float fts = bf_hi(pts[k]), ftt = bf_hi(ptt[k]);
            c11 += fos * fot;
            c12 += fos * ftt + fts * fot;
            float as = fts - ds * fxs;
            float bt = ftt - dt * fxt;
            c22 += as * bt;
            cs  += fos * fts + fot * ftt;
        }
    }

    #pragma unroll
    for (int off = 16; off > 0; off >>= 1) {
        c11 += __shfl_xor(c11, off);
        c12 += __shfl_xor(c12, off);
        c22 += __shfl_xor(c22, off);
        cs  += __shfl_xor(cs,  off);
    }

    if (l == 0) {
        out[q]          = c11;
        out[nq + q]     = c12;
        out[2 * nq + q] = c22;
        out[3 * nq + q] = cs;
    }
}

// ---------------------------------------------------------------------------
extern "C" void kernel_launch(void* const* d_in, const int* in_sizes, int n_in,
                              void* d_out, int out_size, void* d_ws, size_t ws_size,
                              hipStream_t stream) {
    const int*   edges        = (const int*)  d_in[0];
    const int*   adj_row      = (const int*)  d_in[1];
    const int*   adj_col      = (const int*)  d_in[2];
    const float* node_weight  = (const float*)d_in[3];
    const float* node_vectors = (const float*)d_in[4];

    const int EQ = in_sizes[0] / 2;
    const int E  = in_sizes[1];
    const int N  = in_sizes[3];

    // workspace layout
    uint2* cmb   = (uint2*)d_ws;                        // N*192 uint2
    uint2* xs_sl = cmb + (size_t)N * NODE_U2;           // N*64 uint2
    uint2* oh_sl = xs_sl + (size_t)N * 64;              // N*64 uint2
    int* row_ptr = (int*)(oh_sl + (size_t)N * 64);      // [N+1]
    int* cursor  = row_ptr + (N + 1);                   // [N]
    int* cnt     = cursor + N;                          // [N] (deg)
    int* s1      = cnt + N;                             // [256]
    unsigned short* perm = (unsigned short*)(s1 + 256); // [E]

    const int* es = edges;
    const int* et = edges + EQ;
    float* out = (float*)d_out;

    const int nb0 = (N + 255) / 256;   // 196
    const int per_part = (N + 7) / 8;  // 6250

    // --- fused x (both layouts, NT stores) + partitioned histogram ---
    hipMemsetAsync(cnt, 0, (size_t)N * sizeof(int), stream);
    int total_u2 = N * 64;
    x_and_hist_kernel<<<2048, 256, 0, stream>>>(node_vectors, node_weight,
                                                cmb, xs_sl, total_u2, N,
                                                adj_row, cnt, E, per_part);

    // --- CSR scan + partitioned permutation (u16) ---
    block_sum_kernel<<<nb0, 256, 0, stream>>>(cnt, s1, N);
    scan_sums_kernel<<<1, 256, 0, stream>>>(s1, nb0, row_ptr + N);
    scan_block_kernel<<<nb0, 256, 0, stream>>>(cnt, s1, row_ptr, cursor, N);
    scatter_perm_part_kernel<<<2048, 256, 0, stream>>>(adj_row, adj_col,
                                                       cursor, perm, E,
                                                       per_part);

    // --- one_hop / two_hop via XCD-pinned sliced gather (NT dst) ---
    const uint4* xs4 = (const uint4*)xs_sl;
    uint4* oh4 = (uint4*)oh_sl;
    uint4* cmb4 = (uint4*)cmb;
    int nrb = (N + 63) / 64;
    int gblocks = nrb * NSL;
    gather_sliced_kernel<<<gblocks, 256, 0, stream>>>(
        row_ptr, perm, xs4, oh4, cmb4 + SLOT_OH_U4, N);
    gather_sliced_kernel<<<gblocks, 256, 0, stream>>>(
        row_ptr, perm, (const uint4*)oh4, (uint4*)nullptr,
        cmb4 + SLOT_TH_U4, N);

    // --- queries (unsorted, contiguous cmb) ---
    int qthreads = EQ * 32;
    query_kernel<<<(qthreads + 255) / 256, 256, 0, stream>>>(
        es, et, cmb4, cnt, out, EQ);
}

// Round 20
// 229.964 us; speedup vs baseline: 1.0313x; 1.0098x over previous
//
#include <hip/hip_runtime.h>

#define DIM 256
// contiguous combined layout (query path): per node 3 slots (x, oh, th)
#define NODE_U2 192
#define NODE_U4 96
#define SLOT_OH_U4 32
#define SLOT_TH_U4 64

// dimension slicing (gather path): 8 slices x 32 dims (64 B = 4 uint4)
#define NSL 8
// LDS edge-stage capacity (u16)
#define ECAP 2048

typedef unsigned int u32x2 __attribute__((ext_vector_type(2)));
typedef unsigned int u32x4 __attribute__((ext_vector_type(4)));

// ---- bf16 helpers ---------------------------------------------------------
__device__ __forceinline__ unsigned int f2bf_rne(float f) {
    unsigned int u = __float_as_uint(f);
    return (u + 0x7fffu + ((u >> 16) & 1u)) >> 16;
}
__device__ __forceinline__ float bf_lo(unsigned int u) {
    return __uint_as_float(u << 16);
}
__device__ __forceinline__ float bf_hi(unsigned int u) {
    return __uint_as_float(u & 0xffff0000u);
}
__device__ __forceinline__ unsigned int pack2(float a, float b) {
    return f2bf_rne(a) | (f2bf_rne(b) << 16);
}

#define ACC8(v)                                            \
    do {                                                   \
        a0 += bf_lo((v).x); a1 += bf_hi((v).x);            \
        a2 += bf_lo((v).y); a3 += bf_hi((v).y);            \
        a4 += bf_lo((v).z); a5 += bf_hi((v).z);            \
        a6 += bf_lo((v).w); a7 += bf_hi((v).w);            \
    } while (0)

// ---------------------------------------------------------------------------
// 1) fused: x stream (block-local two-pass: coalesced cmb write, then
//    L2-warm re-read -> slice-contiguous xs_sl write) + partitioned hist.
//    Blocks with no stream chunk start the hist immediately (overlap).
// ---------------------------------------------------------------------------
__global__ void x_and_hist_kernel(const float* __restrict__ nv,
                                  const float* __restrict__ w,
                                  uint2* __restrict__ cmb,
                                  uint2* __restrict__ xs_sl,
                                  int N,
                                  const int* __restrict__ adj_row,
                                  int* __restrict__ cnt, int E, int per_part) {
    const float4* nv4 = reinterpret_cast<const float4*>(nv);
    int nchunksX = (N + 63) / 64;
    for (int c = blockIdx.x; c < nchunksX; c += gridDim.x) {
        int node0 = c * 64;
        int nn = N - node0; if (nn > 64) nn = 64;
        // pass A: coalesced read + coalesced cmb x-slot write
        #pragma unroll
        for (int k = 0; k < 16; ++k) {
            int idx = k * 256 + threadIdx.x;    // 0..4095
            int n = idx >> 6;
            int j = idx & 63;
            if (n < nn) {
                int node = node0 + n;
                float4 v = nv4[(size_t)node * 64 + j];
                float wt = w[node];
                u32x2 r;
                r.x = pack2(v.x * wt, v.y * wt);
                r.y = pack2(v.z * wt, v.w * wt);
                __builtin_nontemporal_store(
                    r, reinterpret_cast<u32x2*>(
                           &cmb[(size_t)node * NODE_U2 + j]));
            }
        }
        // pass B: L2-warm re-read in slice order; 4KB-contiguous xs_sl writes
        #pragma unroll
        for (int s = 0; s < NSL; ++s) {
            #pragma unroll
            for (int k2 = 0; k2 < 2; ++k2) {
                int idx = k2 * 256 + threadIdx.x;   // 0..511
                int n = idx >> 3;
                int jj = idx & 7;
                if (n < nn) {
                    int node = node0 + n;
                    float4 v = nv4[(size_t)node * 64 + s * 8 + jj];
                    float wt = w[node];
                    u32x2 r;
                    r.x = pack2(v.x * wt, v.y * wt);
                    r.y = pack2(v.z * wt, v.w * wt);
                    __builtin_nontemporal_store(
                        r, reinterpret_cast<u32x2*>(
                               &xs_sl[((size_t)s * N + node) * 8 + jj]));
                }
            }
        }
    }
    // histogram (XCD-partitioned by row range)
    int bp = blockIdx.x & 7;
    unsigned lo = (unsigned)(bp * per_part);
    int chunk = blockIdx.x >> 3;
    int nchunks = gridDim.x >> 3;
    int E4 = E >> 2;
    for (int i = chunk * 256 + threadIdx.x; i < E4; i += nchunks * 256) {
        int4 r4 = reinterpret_cast<const int4*>(adj_row)[i];
        if ((unsigned)(r4.x - lo) < (unsigned)per_part) atomicAdd(&cnt[r4.x], 1);
        if ((unsigned)(r4.y - lo) < (unsigned)per_part) atomicAdd(&cnt[r4.y], 1);
        if ((unsigned)(r4.z - lo) < (unsigned)per_part) atomicAdd(&cnt[r4.z], 1);
        if ((unsigned)(r4.w - lo) < (unsigned)per_part) atomicAdd(&cnt[r4.w], 1);
    }
    if (bp == 0 && chunk == 0) {
        for (int e = (E & ~3) + threadIdx.x; e < E; e += 256)
            atomicAdd(&cnt[adj_row[e]], 1);
    }
}

// ---------------------------------------------------------------------------
// generic 2-level scan pieces
// ---------------------------------------------------------------------------
__global__ void block_sum_kernel(const int* __restrict__ in,
                                 int* __restrict__ sums, int n) {
    __shared__ int lds[256];
    int i = blockIdx.x * 256 + threadIdx.x;
    lds[threadIdx.x] = (i < n) ? in[i] : 0;
    __syncthreads();
    #pragma unroll
    for (int off = 128; off > 0; off >>= 1) {
        if (threadIdx.x < off) lds[threadIdx.x] += lds[threadIdx.x + off];
        __syncthreads();
    }
    if (threadIdx.x == 0) sums[blockIdx.x] = lds[0];
}

__global__ void scan_sums_kernel(int* __restrict__ sums, int nb,
                                 int* __restrict__ total_out) {
    __shared__ int lds[256];
    int v = (threadIdx.x < nb) ? sums[threadIdx.x] : 0;
    lds[threadIdx.x] = v;
    __syncthreads();
    #pragma unroll
    for (int off = 1; off < 256; off <<= 1) {
        int t = (threadIdx.x >= off) ? lds[threadIdx.x - off] : 0;
        __syncthreads();
        lds[threadIdx.x] += t;
        __syncthreads();
    }
    if (threadIdx.x < nb) sums[threadIdx.x] = lds[threadIdx.x] - v;
    if (threadIdx.x == 255) *total_out = lds[255];
}

__global__ void scan_block_kernel(const int* __restrict__ in,
                                  const int* __restrict__ sums,
                                  int* __restrict__ out1,
                                  int* __restrict__ out2, int n) {
    __shared__ int lds[256];
    int i = blockIdx.x * 256 + threadIdx.x;
    int v = (i < n) ? in[i] : 0;
    lds[threadIdx.x] = v;
    __syncthreads();
    #pragma unroll
    for (int off = 1; off < 256; off <<= 1) {
        int t = (threadIdx.x >= off) ? lds[threadIdx.x - off] : 0;
        __syncthreads();
        lds[threadIdx.x] += t;
        __syncthreads();
    }
    if (i < n) {
        int excl = sums[blockIdx.x] + lds[threadIdx.x] - v;
        out1[i] = excl;
        out2[i] = excl;
    }
}

// ---------------------------------------------------------------------------
// XCD-partitioned permutation build; perm stored as u16 (N < 65536)
// ---------------------------------------------------------------------------
__global__ void scatter_perm_part_kernel(const int* __restrict__ row,
                                         const int* __restrict__ col,
                                         int* __restrict__ cursor,
                                         unsigned short* __restrict__ perm,
                                         int E, int per_part) {
    int bp = blockIdx.x & 7;
    unsigned lo = (unsigned)(bp * per_part);
    int chunk = blockIdx.x >> 3;
    int nchunks = gridDim.x >> 3;
    int E4 = E >> 2;
    for (int i = chunk * 256 + threadIdx.x; i < E4; i += nchunks * 256) {
        int4 r4 = reinterpret_cast<const int4*>(row)[i];
        int e = i << 2;
        if ((unsigned)(r4.x - lo) < (unsigned)per_part) {
            int pos = atomicAdd(&cursor[r4.x], 1);
            perm[pos] = (unsigned short)col[e];
        }
        if ((unsigned)(r4.y - lo) < (unsigned)per_part) {
            int pos = atomicAdd(&cursor[r4.y], 1);
            perm[pos] = (unsigned short)col[e + 1];
        }
        if ((unsigned)(r4.z - lo) < (unsigned)per_part) {
            int pos = atomicAdd(&cursor[r4.z], 1);
            perm[pos] = (unsigned short)col[e + 2];
        }
        if ((unsigned)(r4.w - lo) < (unsigned)per_part) {
            int pos = atomicAdd(&cursor[r4.w], 1);
            perm[pos] = (unsigned short)col[e + 3];
        }
    }
    if (bp == 0 && chunk == 0) {
        for (int e = (E & ~3) + threadIdx.x; e < E; e += 256) {
            int pos = atomicAdd(&cursor[row[e]], 1);
            perm[pos] = (unsigned short)col[e];
        }
    }
}

// ---------------------------------------------------------------------------
// Dimension-sliced gather with LDS-staged u16 edge lists; NT dst stores keep
// the per-XCD 3.2MB src slab L2-resident.
// ---------------------------------------------------------------------------
__global__ void gather_sliced_kernel(const int* __restrict__ row_ptr,
                                     const unsigned short* __restrict__ perm,
                                     const uint4* __restrict__ src_sl,
                                     uint4* __restrict__ dst_sl,
                                     uint4* __restrict__ dst_cmb_slot,
                                     int N) {
    __shared__ unsigned short eidx[ECAP];
    int s = blockIdx.x & (NSL - 1);
    int rb = blockIdx.x >> 3;
    int r0 = rb * 64;
    int rlim = r0 + 64 < N ? r0 + 64 : N;
    int beg0 = row_ptr[r0];
    int end0 = row_ptr[rlim];
    int L = end0 - beg0;
    int Lc = L < ECAP ? L : ECAP;
    for (int i = threadIdx.x; i < Lc; i += 256) eidx[i] = perm[beg0 + i];
    __syncthreads();

    int g = threadIdx.x >> 2;
    int j = threadIdx.x & 3;
    int r = r0 + g;
    if (r >= N) return;

    int beg = row_ptr[r];
    int end = row_ptr[r + 1];
    const uint4* base = src_sl + (size_t)s * N * 4;

    float a0 = 0.f, a1 = 0.f, a2 = 0.f, a3 = 0.f;
    float a4 = 0.f, a5 = 0.f, a6 = 0.f, a7 = 0.f;

    if (L <= ECAP) {
        int o = beg - beg0;
        int cnt = end - beg;
        int k = 0;
        for (; k + 3 < cnt; k += 4) {
            int c0 = eidx[o + k];
            int c1 = eidx[o + k + 1];
            int c2 = eidx[o + k + 2];
            int c3 = eidx[o + k + 3];
            uint4 v0 = base[(size_t)c0 * 4 + j];
            uint4 v1 = base[(size_t)c1 * 4 + j];
            uint4 v2 = base[(size_t)c2 * 4 + j];
            uint4 v3 = base[(size_t)c3 * 4 + j];
            ACC8(v0); ACC8(v1); ACC8(v2); ACC8(v3);
        }
        for (; k < cnt; ++k) {
            uint4 v = base[(size_t)eidx[o + k] * 4 + j];
            ACC8(v);
        }
    } else {
        for (int e = beg; e < end; ++e) {
            uint4 v = base[(size_t)perm[e] * 4 + j];
            ACC8(v);
        }
    }

    u32x4 o4;
    o4.x = pack2(a0, a1);
    o4.y = pack2(a2, a3);
    o4.z = pack2(a4, a5);
    o4.w = pack2(a6, a7);
    if (dst_sl)
        __builtin_nontemporal_store(
            o4, reinterpret_cast<u32x4*>(&dst_sl[((size_t)s * N + r) * 4 + j]));
    __builtin_nontemporal_store(
        o4, reinterpret_cast<u32x4*>(
                &dst_cmb_slot[(size_t)r * NODE_U4 + s * 4 + j]));
}

// ---------------------------------------------------------------------------
// Query: 32 lanes per query (uint4 loads), 2 queries per wave (contiguous cmb)
// ---------------------------------------------------------------------------
__global__ void query_kernel(const int* __restrict__ es,
                             const int* __restrict__ et,
                             const uint4* __restrict__ cmb4,
                             const int* __restrict__ deg,
                             float* __restrict__ out, int nq) {
    int gid = blockIdx.x * blockDim.x + threadIdx.x;
    int q = gid >> 5;
    if (q >= nq) return;
    int l = gid & 31;

    int s = es[q];
    int t = et[q];

    const uint4* ns = cmb4 + (size_t)s * NODE_U4;
    const uint4* nt = cmb4 + (size_t)t * NODE_U4;

    uint4 vxs = ns[l];
    uint4 vos = ns[SLOT_OH_U4 + l];
    uint4 vts = ns[SLOT_TH_U4 + l];
    uint4 vxt = nt[l];
    uint4 vot = nt[SLOT_OH_U4 + l];
    uint4 vtt = nt[SLOT_TH_U4 + l];
    float ds = (float)deg[s];
    float dt = (float)deg[t];

    float c11 = 0.f, c12 = 0.f, c22 = 0.f, cs = 0.f;
    const unsigned int* pxs = (const unsigned int*)&vxs;
    const unsigned int* pxt = (const unsigned int*)&vxt;
    const unsigned int* pos_ = (const unsigned int*)&vos;
    const unsigned int* pot = (const unsigned int*)&vot;
    const unsigned int* pts = (const unsigned int*)&vts;
    const unsigned int* ptt = (const unsigned int*)&vtt;
    #pragma unroll
    for (int k = 0; k < 4; ++k) {
        {
            float fxs = bf_lo(pxs[k]), fxt = bf_lo(pxt[k]);
            float fos = bf_lo(pos_[k]), fot = bf_lo(pot[k]);
            float fts = bf_lo(pts[k]), ftt = bf_lo(ptt[k]);
            c11 += fos * fot;
            c12 += fos * ftt + fts * fot;
            float as = fts - ds * fxs;
            float bt = ftt - dt * fxt;
            c22 += as * bt;
            cs  += fos * fts + fot * ftt;
        }
        {
            float fxs = bf_hi(pxs[k]), fxt = bf_hi(pxt[k]);
            float fos = bf_hi(pos_[k]), fot = bf_hi(pot[k]);
            float fts = bf_hi(pts[k]), ftt = bf_hi(ptt[k]);
            c11 += fos * fot;
            c12 += fos * ftt + fts * fot;
            float as = fts - ds * fxs;
            float bt = ftt - dt * fxt;
            c22 += as * bt;
            cs  += fos * fts + fot * ftt;
        }
    }

    #pragma unroll
    for (int off = 16; off > 0; off >>= 1) {
        c11 += __shfl_xor(c11, off);
        c12 += __shfl_xor(c12, off);
        c22 += __shfl_xor(c22, off);
        cs  += __shfl_xor(cs,  off);
    }

    if (l == 0) {
        out[q]          = c11;
        out[nq + q]     = c12;
        out[2 * nq + q] = c22;
        out[3 * nq + q] = cs;
    }
}

// ---------------------------------------------------------------------------
extern "C" void kernel_launch(void* const* d_in, const int* in_sizes, int n_in,
                              void* d_out, int out_size, void* d_ws, size_t ws_size,
                              hipStream_t stream) {
    const int*   edges        = (const int*)  d_in[0];
    const int*   adj_row      = (const int*)  d_in[1];
    const int*   adj_col      = (const int*)  d_in[2];
    const float* node_weight  = (const float*)d_in[3];
    const float* node_vectors = (const float*)d_in[4];

    const int EQ = in_sizes[0] / 2;
    const int E  = in_sizes[1];
    const int N  = in_sizes[3];

    // workspace layout
    uint2* cmb   = (uint2*)d_ws;                        // N*192 uint2
    uint2* xs_sl = cmb + (size_t)N * NODE_U2;           // N*64 uint2
    uint2* oh_sl = xs_sl + (size_t)N * 64;              // N*64 uint2
    int* row_ptr = (int*)(oh_sl + (size_t)N * 64);      // [N+1]
    int* cursor  = row_ptr + (N + 1);                   // [N]
    int* cnt     = cursor + N;                          // [N] (deg)
    int* s1      = cnt + N;                             // [256]
    unsigned short* perm = (unsigned short*)(s1 + 256); // [E]

    const int* es = edges;
    const int* et = edges + EQ;
    float* out = (float*)d_out;

    const int nb0 = (N + 255) / 256;   // 196
    const int per_part = (N + 7) / 8;  // 6250

    // --- fused x (block-local two-pass) + partitioned histogram ---
    hipMemsetAsync(cnt, 0, (size_t)N * sizeof(int), stream);
    x_and_hist_kernel<<<2048, 256, 0, stream>>>(node_vectors, node_weight,
                                                cmb, xs_sl, N,
                                                adj_row, cnt, E, per_part);

    // --- CSR scan + partitioned permutation (u16) ---
    block_sum_kernel<<<nb0, 256, 0, stream>>>(cnt, s1, N);
    scan_sums_kernel<<<1, 256, 0, stream>>>(s1, nb0, row_ptr + N);
    scan_block_kernel<<<nb0, 256, 0, stream>>>(cnt, s1, row_ptr, cursor, N);
    scatter_perm_part_kernel<<<2048, 256, 0, stream>>>(adj_row, adj_col,
                                                       cursor, perm, E,
                                                       per_part);

    // --- one_hop / two_hop via XCD-pinned sliced gather (NT dst) ---
    const uint4* xs4 = (const uint4*)xs_sl;
    uint4* oh4 = (uint4*)oh_sl;
    uint4* cmb4 = (uint4*)cmb;
    int nrb = (N + 63) / 64;
    int gblocks = nrb * NSL;
    gather_sliced_kernel<<<gblocks, 256, 0, stream>>>(
        row_ptr, perm, xs4, oh4, cmb4 + SLOT_OH_U4, N);
    gather_sliced_kernel<<<gblocks, 256, 0, stream>>>(
        row_ptr, perm, (const uint4*)oh4, (uint4*)nullptr,
        cmb4 + SLOT_TH_U4, N);

    // --- queries (unsorted, contiguous cmb) ---
    int qthreads = EQ * 32;
    query_kernel<<<(qthreads + 255) / 256, 256, 0, stream>>>(
        es, et, cmb4, cnt, out, EQ);
}